// Round 5
// baseline (404.081 us; speedup 1.0000x reference)
//
#include <hip/hip_runtime.h>
#include <math.h>

// Fully-fused pipeline, one heavyweight kernel + prep + softmax.
// R5: PHASE-SPLIT to kill register pressure (R3/R4: allocator pins 128 VGPR
// and spills ~11MB whatever attributes say -> make true pressure fit 128).
//   Phase 1 (conv1+pool1): block = 16 series; each wave owns ONE channel
//     group of 8 (wave-uniform -> weights live in SGPRs via readfirstlane,
//     zero VGPR cost; v_fmac_f32 takes 1 SGPR operand). Lanes = 16 series x
//     4 position-runs ({0-7,8-15,16-22,23-29}). Two passes of 4 channels
//     (44 SGPR each). Pooled bf16 -> LDS h1[16][30][32] (row stride padded
//     to 968 ushorts: 484 mod 32 = 4 -> conflict-minimal b128 reads).
//   Phase 2: barrier; conv2 A-frags = ds_read_b128 from h1 in EXACT MFMA-A
//     layout (identical bits to the old in-register path); wave g: conv2
//     nt=g -> bias+relu+pool2 -> sh2 tile; barrier; conv3 nt3={2g,2g+1}
//     (K=256 MFMA) -> relu -> logits partials vs wl -> butterfly -> red ->
//     partials[2048][3].
//   k_soft: 1 block: logits = sum of 8 partials + bl, softmax -> out.
// Grid 2048x256 = 8 waves/SIMD of work; ~110 VGPR + 39.5KB LDS -> 4-5 waves
// resident/SIMD: latency hidden by TLP, no spills, no register pipeline.
// conv1/conv2/conv3 chains are order-identical to R0-R4.

typedef __attribute__((ext_vector_type(8))) short bf16x8;
typedef __attribute__((ext_vector_type(4))) float f32x4;

__device__ __forceinline__ ushort f2bf(float f) {
    union { float f; uint u; } c; c.f = f;
    return (ushort)((c.u + 0x7FFFu + ((c.u >> 16) & 1u)) >> 16);   // RNE
}

__device__ __forceinline__ float rfl(float f) {      // wave-uniform -> SGPR
    return __int_as_float(__builtin_amdgcn_readfirstlane(__float_as_int(f)));
}

#define S2  264   // sh2 row stride (ushorts): 528B rows, 16B-aligned
#define H1S 968   // h1 row stride (ushorts): 30*32+8; 484 dwords %32 = 4

__global__ void k0_prep(const float* __restrict__ w2, ushort* __restrict__ w2b,
                        const float* __restrict__ w3, ushort* __restrict__ w3b) {
    int i = blockIdx.x * 256 + threadIdx.x;
    if (i < 6144) {                     // w2[c][ci][d] -> w2b[c][d*32+ci]
        int c = i / 96, r = i - c * 96;
        int ci = r / 3, d = r - ci * 3;
        w2b[c * 96 + d * 32 + ci] = f2bf(w2[i]);
    }
    int j = i - 6144;
    if (j >= 0 && j < 32768) w3b[j] = f2bf(w3[j]);
}

// tap T in [-1,40] of pooled-window p (floats x[40p-1 .. 40p+40])
#define XT1(T) ((T) < 0 ? lo : (T) >= 40 ? hi :                                \
    ((T) & 3) == 0 ? c_[(T) >> 2].x :                                          \
    ((T) & 3) == 1 ? c_[(T) >> 2].y :                                          \
    ((T) & 3) == 2 ? c_[(T) >> 2].z : c_[(T) >> 2].w)

__global__ __launch_bounds__(256) void k_fused(
    const float* __restrict__ x,     // [32768][1216]
    const float* __restrict__ w1,    // [32][10]
    const float* __restrict__ b1,    // [32]
    const ushort* __restrict__ w2b,  // [64][96]
    const float* __restrict__ b2,    // [64]
    const ushort* __restrict__ w3b,  // [128][256]
    const float* __restrict__ b3,    // [128]
    const float* __restrict__ wl,    // [3][16384]
    float* __restrict__ partials)    // [2048][3]
{
    __shared__ ushort h1[16 * H1S];         // conv1-pooled bf16 [16][30][32]
    __shared__ ushort sh2[16 * S2];         // conv2-pooled bf16 tile (16x256)
    __shared__ float red[4][3];
    const int wave = threadIdx.x >> 6, lane = threadIdx.x & 63;
    const int lm   = lane & 15, quad = lane >> 4;
    const int bn0  = blockIdx.x * 16;
    const float* xr = x + (size_t)(bn0 + lm) * 1216;
    const float4* xp4 = (const float4*)xr;

    // ---- phase 1: conv1 (K=10,s=8,p=1) + relu + pool5 ----
    // wave = channel group (8 ch), lane = (series lm, position run quad)
    const int q0p = (quad < 2) ? quad * 8 : 16 + (quad - 2) * 7;
    const int qcn = (quad < 2) ? 8 : 7;

    for (int pp = 0; pp < 2; ++pp) {        // 4 channels per pass (SGPR w)
        float ws[4][10], wb[4];
        #pragma unroll
        for (int h = 0; h < 4; ++h) {
            const int ch = wave * 8 + pp * 4 + h;
            const float* wr = w1 + ch * 10;
            #pragma unroll
            for (int k = 0; k < 10; ++k) ws[h][k] = rfl(wr[k]);
            wb[h] = rfl(b1[ch]);
        }
        for (int j = 0; j < qcn; ++j) {     // divergent bound: quads 2,3 do 7
            const int p = q0p + j;
            float4 c_[10];
            #pragma unroll
            for (int i = 0; i < 10; ++i) c_[i] = xp4[10 * p + i];
            const float hi = xr[40 * p + 40];
            const float lo = (p > 0) ? xr[40 * p - 1] : 0.f;
            float mx[4];
            #pragma unroll
            for (int h = 0; h < 4; ++h) mx[h] = 0.f;    // relu folded in pool
            #pragma unroll
            for (int dt = 0; dt < 5; ++dt) {
                float a[4];
                #pragma unroll
                for (int h = 0; h < 4; ++h) a[h] = wb[h];
                #pragma unroll
                for (int k = 0; k < 10; ++k) {
                    const float xv = XT1(8 * dt + k - 1);
                    #pragma unroll
                    for (int h = 0; h < 4; ++h) a[h] = fmaf(ws[h][k], xv, a[h]);
                }
                #pragma unroll
                for (int h = 0; h < 4; ++h) mx[h] = fmaxf(mx[h], a[h]);
            }
            union { ushort u[4]; uint2 v; } ov;
            #pragma unroll
            for (int h = 0; h < 4; ++h) ov.u[h] = f2bf(mx[h]);
            *(uint2*)&h1[lm * H1S + p * 32 + wave * 8 + pp * 4] = ov.v;
        }
    }
    __syncthreads();

    // ---- phase 2a: conv2 MFMA (wave's nt = wave) + bias+relu+pool2 ----
    // A-frag: lane(quad,lm) = series lm, ch quad*8..+7 (same bits as before)
    const float bias2v = b2[wave * 16 + lm];
    f32x4 cur1 = (f32x4){-3e38f, -3e38f, -3e38f, -3e38f};
    for (int q = 0; q < 10; ++q) {
        f32x4 a1v = (f32x4){0.f, 0.f, 0.f, 0.f};
        #pragma unroll
        for (int kc = 0; kc < 3; ++kc) {
            const int p = 3 * q + kc;
            bf16x8 afv = *(const bf16x8*)(h1 + lm * H1S + p * 32 + quad * 8);
            bf16x8 bfr = *(const bf16x8*)(w2b + (wave * 16 + lm) * 96 + kc * 32 + quad * 8);
            a1v = __builtin_amdgcn_mfma_f32_16x16x32_bf16(afv, bfr, a1v, 0, 0, 0);
        }
        // pool2 windows over q: {0,1},{2,3,4},{5,6,7},{8,9}
        const bool fresh = (q == 0 || q == 2 || q == 5 || q == 8);
        #pragma unroll
        for (int r = 0; r < 4; ++r)
            cur1[r] = fresh ? a1v[r] : fmaxf(cur1[r], a1v[r]);
        if (q == 1 || q == 4 || q == 7 || q == 9) {     // window close
            const int w = (q == 1) ? 0 : (q == 4) ? 1 : (q == 7) ? 2 : 3;
            #pragma unroll
            for (int r = 0; r < 4; ++r) {
                float f = fmaxf(cur1[r] + bias2v, 0.f);
                sh2[(quad * 4 + r) * S2 + (wave * 16 + lm) * 4 + w] = f2bf(f);
            }
        }
    }
    __syncthreads();

    // ---- phase 2b: conv3 GEMM (K=256; wave's nt3 = 2*wave, 2*wave+1) ----
    bf16x8 afr[8];
    #pragma unroll
    for (int kc = 0; kc < 8; ++kc)          // A-frag: row lm, 16B contiguous
        afr[kc] = *(const bf16x8*)(sh2 + lm * S2 + kc * 32 + quad * 8);

    const int node0 = bn0 & 127;
    const float* wlr = wl + (node0 + quad * 4) * 128 + lm;
    float a0 = 0.f, a1 = 0.f, a2 = 0.f;
    #pragma unroll
    for (int t3 = 0; t3 < 2; ++t3) {
        const int nt3 = wave * 2 + t3;
        f32x4 acc3 = (f32x4){0.f, 0.f, 0.f, 0.f};
        const ushort* bb = w3b + (size_t)(nt3 * 16 + lm) * 256 + quad * 8;
        #pragma unroll
        for (int kc = 0; kc < 8; ++kc) {
            bf16x8 bf3 = *(const bf16x8*)(bb + kc * 32);
            acc3 = __builtin_amdgcn_mfma_f32_16x16x32_bf16(afr[kc], bf3, acc3, 0, 0, 0);
        }
        const float b3v = b3[nt3 * 16 + lm];
        #pragma unroll
        for (int r = 0; r < 4; ++r) {       // feat value, never materialized
            float f = fmaxf(acc3[r] + b3v, 0.f);
            const float* wp = wlr + r * 128 + nt3 * 16;
            a0 = fmaf(f, wp[0],     a0);
            a1 = fmaf(f, wp[16384], a1);
            a2 = fmaf(f, wp[32768], a2);
        }
    }

    #pragma unroll
    for (int off = 32; off > 0; off >>= 1) {
        a0 += __shfl_xor(a0, off);
        a1 += __shfl_xor(a1, off);
        a2 += __shfl_xor(a2, off);
    }
    if (lane == 0) { red[wave][0] = a0; red[wave][1] = a1; red[wave][2] = a2; }
    __syncthreads();
    if (threadIdx.x < 3) {
        float s = red[0][threadIdx.x] + red[1][threadIdx.x]
                + red[2][threadIdx.x] + red[3][threadIdx.x];
        partials[blockIdx.x * 3 + threadIdx.x] = s;
    }
}

// logits = sum of 8 partials rows + bl -> softmax
__global__ void k_soft(const float* __restrict__ partials,
                       const float* __restrict__ bl,
                       float* __restrict__ out) {
    const int b = threadIdx.x;      // 256 batches, 1 block
    float l0 = bl[0], l1 = bl[1], l2 = bl[2];
    #pragma unroll
    for (int j = 0; j < 8; ++j) {
        const float* pr = partials + (8*b + j) * 3;
        l0 += pr[0]; l1 += pr[1]; l2 += pr[2];
    }
    float m  = fmaxf(l0, fmaxf(l1, l2));
    float e0 = expf(l0 - m), e1 = expf(l1 - m), e2 = expf(l2 - m);
    float s  = e0 + e1 + e2;
    out[b*3+0] = e0 / s; out[b*3+1] = e1 / s; out[b*3+2] = e2 / s;
}

extern "C" void kernel_launch(void* const* d_in, const int* in_sizes, int n_in,
                              void* d_out, int out_size, void* d_ws, size_t ws_size,
                              hipStream_t stream) {
    const float* x  = (const float*)d_in[0];
    const float* w1 = (const float*)d_in[1];
    const float* b1 = (const float*)d_in[2];
    const float* w2 = (const float*)d_in[3];
    const float* b2 = (const float*)d_in[4];
    const float* w3 = (const float*)d_in[5];
    const float* b3 = (const float*)d_in[6];
    const float* wl = (const float*)d_in[7];
    const float* bl = (const float*)d_in[8];
    float* out = (float*)d_out;

    // tiny ws: w2b 12KB | w3b 64KB | partials 24KB
    ushort* w2b      = (ushort*)d_ws;
    ushort* w3b      = (ushort*)((char*)d_ws + 16384);
    float*  partials = (float*)((char*)d_ws + 16384 + 65536);

    k0_prep<<<152, 256, 0, stream>>>(w2, w2b, w3, w3b);
    k_fused<<<2048, 256, 0, stream>>>(x, w1, b1, w2b, b2, w3b, b3, wl, partials);
    k_soft<<<1, 256, 0, stream>>>(partials, bl, out);
}

// Round 6
// 300.076 us; speedup vs baseline: 1.3466x; 1.3466x over previous
//
#include <hip/hip_runtime.h>
#include <math.h>

// Fully-fused pipeline, one heavyweight kernel + prep + softmax.
// R6: R3's compute mapping kept BIT-IDENTICAL; the x-load path is replaced
// by coalesced LDS staging. Evidence: R5 proved occupancy is not the lever
// (40% occ, worse time); R3/R5 stall on scattered global loads (each load
// inst touches 16-64 cache lines: lanes read 16 different 4864B-strided
// rows). Now each block (128 thr = 2 waves, 32 series) stages the per-q
// window region x[32 rows][128 floats] into LDS with CONTIGUOUS float4 runs
// (32 consecutive lanes cover one row -> 2-3 lines per instruction), then
// conv1 reads taps from LDS (quads broadcast same address; row stride 132
// floats = 4 mod 32 banks -> conflict-free by pairs). Conv1/conv2/conv3
// arithmetic order identical to R0/R3 (absmax unchanged).
//   k0    : w2 [64][32][3] -> w2b bf16 [64][96] (k=d*32+ci); w3 -> w3b bf16
//   k_fused: per q: stage xs -> conv1+pool1 per-lane in EXACT MFMA-A layout
//     -> conv2 = 16x16x32 MFMA vs w2b -> bias+relu+pool2 -> bf16 into
//     wave-private sh2 tile (the only transpose) -> after loop: conv3 GEMM
//     (K=256) vs w3b -> relu -> logits partials vs wl -> wave butterfly
//     -> per-block partial[1024][3]
//   k_soft: 1 block: logits = sum of 4 partials + bl, softmax -> out.

typedef __attribute__((ext_vector_type(8))) short bf16x8;
typedef __attribute__((ext_vector_type(4))) float f32x4;

__device__ __forceinline__ ushort f2bf(float f) {
    union { float f; uint u; } c; c.f = f;
    return (ushort)((c.u + 0x7FFFu + ((c.u >> 16) & 1u)) >> 16);   // RNE
}

#define S2  264   // sh2 row stride (ushorts): 528B rows, 16B-aligned
#define XSS 132   // xs row stride (floats): 528B rows; 132%32=4 -> 2-way free

__global__ void k0_prep(const float* __restrict__ w2, ushort* __restrict__ w2b,
                        const float* __restrict__ w3, ushort* __restrict__ w3b) {
    int i = blockIdx.x * 256 + threadIdx.x;
    if (i < 6144) {                     // w2[c][ci][d] -> w2b[c][d*32+ci]
        int c = i / 96, r = i - c * 96;
        int ci = r / 3, d = r - ci * 3;
        w2b[c * 96 + d * 32 + ci] = f2bf(w2[i]);
    }
    int j = i - 6144;
    if (j >= 0 && j < 32768) w3b[j] = f2bf(w3[j]);
}

// tap T in [-1,40] of the current window (floats x[40p-1 .. 40p+40])
#define XT1(T) ((T) < 0 ? lo : (T) >= 40 ? hi :                                \
    ((T) & 3) == 0 ? c_[(T) >> 2].x :                                          \
    ((T) & 3) == 1 ? c_[(T) >> 2].y :                                          \
    ((T) & 3) == 2 ? c_[(T) >> 2].z : c_[(T) >> 2].w)

__global__ __launch_bounds__(128) void k_fused(
    const float* __restrict__ x,     // [32768][1216]
    const float* __restrict__ w1,    // [32][10]
    const float* __restrict__ b1,    // [32]
    const ushort* __restrict__ w2b,  // [64][96]
    const float* __restrict__ b2,    // [64]
    const ushort* __restrict__ w3b,  // [128][256]
    const float* __restrict__ b3,    // [128]
    const float* __restrict__ wl,    // [3][16384]
    float* __restrict__ partials)    // [1024][3]
{
    __shared__ __align__(16) float xs[32 * XSS];   // staged x window region
    __shared__ ushort sh2[2 * 16 * S2];            // wave-private 16x256 bf16
    __shared__ float red[2][3];
    const int tid  = threadIdx.x;
    const int wave = tid >> 6, lane = tid & 63;
    const int lm   = lane & 15, quad = lane >> 4;
    const int bn0b = blockIdx.x * 32;              // block's first series
    const int bn0  = bn0b + wave * 16;             // wave's first series
    ushort* shw = sh2 + wave * 16 * S2;

    // hoist this lane's conv1 weights: channels quad*8..quad*8+7
    float wv[8][10], b1v[8];
    #pragma unroll
    for (int h = 0; h < 8; ++h) {
        const float* wr = w1 + (quad * 8 + h) * 10;     // 4 distinct addrs/wave
        #pragma unroll
        for (int kk = 0; kk < 5; ++kk) {
            float2 t = *(const float2*)(wr + 2 * kk);
            wv[h][2*kk] = t.x; wv[h][2*kk+1] = t.y;
        }
        b1v[h] = b1[quad * 8 + h];
    }
    float bias2[4];
    #pragma unroll
    for (int nt = 0; nt < 4; ++nt) bias2[nt] = b2[nt * 16 + lm];

    // ---- per q: stage -> conv1 -> conv2 MFMA -> pool2 ----
    f32x4 cur[4];
    #pragma unroll
    for (int nt = 0; nt < 4; ++nt) cur[nt] = (f32x4){-3e38f,-3e38f,-3e38f,-3e38f};

    for (int q = 0; q < 10; ++q) {
        // stage x[32 rows][floats 120q-4 .. 120q+123] -> xs, coalesced:
        // 32 consecutive lanes cover one row's 512B contiguously.
        const int fq = 120 * q - 4;
        #pragma unroll
        for (int j = 0; j < 8; ++j) {
            const int idx = tid + 128 * j;
            const int row = idx >> 5, c4 = idx & 31;
            const int off = fq + 4 * c4;
            const float* src = x + (size_t)(bn0b + row) * 1216 + (off < 0 ? 0 : off);
            float4 v = *(const float4*)src;
            if (off < 0) v.w = 0.f;        // x[-1] pad (only float idx 3 used)
            *(float4*)&xs[row * XSS + 4 * c4] = v;
        }
        __syncthreads();

        f32x4 acc[4];
        #pragma unroll
        for (int nt = 0; nt < 4; ++nt) acc[nt] = (f32x4){0.f,0.f,0.f,0.f};

        #pragma unroll
        for (int kc = 0; kc < 3; ++kc) {    // window p = 3q+kc
            const float* xw = xs + (wave * 16 + lm) * XSS + 40 * kc;
            const float lo = xw[3];
            float4 c_[10];
            #pragma unroll
            for (int i = 0; i < 10; ++i) c_[i] = *(const float4*)&xw[4 + 4 * i];
            const float hi = xw[44];

            float mx[8];
            #pragma unroll
            for (int h = 0; h < 8; ++h) mx[h] = 0.f;    // relu folded in pool
            #pragma unroll
            for (int dt = 0; dt < 5; ++dt) {            // conv1 K=10 s=8 p=1
                float a[8];
                #pragma unroll
                for (int h = 0; h < 8; ++h) a[h] = b1v[h];
                #pragma unroll
                for (int k = 0; k < 10; ++k) {
                    const float xv = XT1(8 * dt + k - 1);
                    #pragma unroll
                    for (int h = 0; h < 8; ++h) a[h] = fmaf(wv[h][k], xv, a[h]);
                }
                #pragma unroll
                for (int h = 0; h < 8; ++h) mx[h] = fmaxf(mx[h], a[h]);
            }
            union { ushort u[8]; bf16x8 v; } af;
            #pragma unroll
            for (int h = 0; h < 8; ++h) af.u[h] = f2bf(mx[h]);
            #pragma unroll
            for (int nt = 0; nt < 4; ++nt) {   // w2b frags from L1 (12KB hot)
                bf16x8 bfr = *(const bf16x8*)(w2b + (nt*16+lm)*96 + kc*32 + quad*8);
                acc[nt] = __builtin_amdgcn_mfma_f32_16x16x32_bf16(af.v, bfr, acc[nt], 0, 0, 0);
            }
        }

        // pool2 windows over q: {0,1},{2,3,4},{5,6,7},{8,9}  (wave-uniform)
        const bool fresh = (q == 0 || q == 2 || q == 5 || q == 8);
        #pragma unroll
        for (int nt = 0; nt < 4; ++nt)
            #pragma unroll
            for (int r = 0; r < 4; ++r)
                cur[nt][r] = fresh ? acc[nt][r] : fmaxf(cur[nt][r], acc[nt][r]);

        if (q == 1 || q == 4 || q == 7 || q == 9) {     // window close
            const int w = (q == 1) ? 0 : (q == 4) ? 1 : (q == 7) ? 2 : 3;
            #pragma unroll
            for (int nt = 0; nt < 4; ++nt)
                #pragma unroll
                for (int r = 0; r < 4; ++r) {
                    float f = fmaxf(cur[nt][r] + bias2[nt], 0.f);
                    shw[(quad*4 + r) * S2 + (nt*16 + lm) * 4 + w] = f2bf(f);
                }
        }
        __syncthreads();                    // WAR: next q's staging vs reads
    }

    // ---- conv3 GEMM (16 series x 128 cols, K=256) + logits partials
    // (sh2 tile written by this wave only; lgkm ordering within wave)
    bf16x8 afr[8];
    #pragma unroll
    for (int kc = 0; kc < 8; ++kc)          // A-frag: row lm, 16B contiguous
        afr[kc] = *(const bf16x8*)(shw + lm * S2 + kc * 32 + quad * 8);

    const int node0 = bn0 & 127;
    const float* wlr = wl + (node0 + quad * 4) * 128 + lm;
    float a0 = 0.f, a1 = 0.f, a2 = 0.f;
    for (int nt3 = 0; nt3 < 8; ++nt3) {     // dynamic: small icache
        f32x4 acc3 = (f32x4){0.f, 0.f, 0.f, 0.f};
        const ushort* bb = w3b + (size_t)(nt3 * 16 + lm) * 256 + quad * 8;
        #pragma unroll
        for (int kc = 0; kc < 8; ++kc) {
            bf16x8 bf3 = *(const bf16x8*)(bb + kc * 32);
            acc3 = __builtin_amdgcn_mfma_f32_16x16x32_bf16(afr[kc], bf3, acc3, 0, 0, 0);
        }
        const float b3v = b3[nt3 * 16 + lm];
        #pragma unroll
        for (int r = 0; r < 4; ++r) {       // feat value, never materialized
            float f = fmaxf(acc3[r] + b3v, 0.f);
            const float* wp = wlr + r * 128 + nt3 * 16;
            a0 = fmaf(f, wp[0],     a0);
            a1 = fmaf(f, wp[16384], a1);
            a2 = fmaf(f, wp[32768], a2);
        }
    }

    #pragma unroll
    for (int off = 32; off > 0; off >>= 1) {
        a0 += __shfl_xor(a0, off);
        a1 += __shfl_xor(a1, off);
        a2 += __shfl_xor(a2, off);
    }
    if (lane == 0) { red[wave][0] = a0; red[wave][1] = a1; red[wave][2] = a2; }
    __syncthreads();
    if (threadIdx.x < 3) {
        float s = red[0][threadIdx.x] + red[1][threadIdx.x];
        partials[blockIdx.x * 3 + threadIdx.x] = s;
    }
}

// logits = sum of 4 partials rows + bl -> softmax
__global__ void k_soft(const float* __restrict__ partials,
                       const float* __restrict__ bl,
                       float* __restrict__ out) {
    const int b = threadIdx.x;      // 256 batches, 1 block
    float l0 = bl[0], l1 = bl[1], l2 = bl[2];
    #pragma unroll
    for (int j = 0; j < 4; ++j) {
        const float* pr = partials + (4*b + j) * 3;
        l0 += pr[0]; l1 += pr[1]; l2 += pr[2];
    }
    float m  = fmaxf(l0, fmaxf(l1, l2));
    float e0 = expf(l0 - m), e1 = expf(l1 - m), e2 = expf(l2 - m);
    float s  = e0 + e1 + e2;
    out[b*3+0] = e0 / s; out[b*3+1] = e1 / s; out[b*3+2] = e2 / s;
}

extern "C" void kernel_launch(void* const* d_in, const int* in_sizes, int n_in,
                              void* d_out, int out_size, void* d_ws, size_t ws_size,
                              hipStream_t stream) {
    const float* x  = (const float*)d_in[0];
    const float* w1 = (const float*)d_in[1];
    const float* b1 = (const float*)d_in[2];
    const float* w2 = (const float*)d_in[3];
    const float* b2 = (const float*)d_in[4];
    const float* w3 = (const float*)d_in[5];
    const float* b3 = (const float*)d_in[6];
    const float* wl = (const float*)d_in[7];
    const float* bl = (const float*)d_in[8];
    float* out = (float*)d_out;

    // tiny ws: w2b 12KB | w3b 64KB | partials 12KB
    ushort* w2b      = (ushort*)d_ws;
    ushort* w3b      = (ushort*)((char*)d_ws + 16384);
    float*  partials = (float*)((char*)d_ws + 16384 + 65536);

    k0_prep<<<152, 256, 0, stream>>>(w2, w2b, w3, w3b);
    k_fused<<<1024, 128, 0, stream>>>(x, w1, b1, w2b, b2, w3b, b3, wl, partials);
    k_soft<<<1, 256, 0, stream>>>(partials, bl, out);
}

// Round 7
// 257.321 us; speedup vs baseline: 1.5703x; 1.1662x over previous
//
#include <hip/hip_runtime.h>
#include <math.h>

// Fully-fused pipeline, one heavyweight kernel + prep + softmax.
// R7: conv1 moves to MFMA. R3..R6 established the bound is the conv1 fp32
// VALU stream (~29K cy/wave) + serial feed, not memory/occupancy. Conv1 is
// matmul-shaped: D[ch][series] = sum_j w1[ch][j] x[series][8t-1+j], MFMA
// 16x16x32 with M=ch(16/half), N=16 series (the wave tile), K slots 3..12
// holding taps (the +3 shift makes every B-frag a 16B-ALIGNED contiguous
// LDS read at plane[series][8*tl + 8*(quad&1)]). t is a sequential loop ->
// pool1 is per-lane fmax, no cross-lane ops.
// NUMERICS: x and w1 are hi/lo bf16-split (v = hi + lo). A-slots 3..12 =
// w_hi, 19..28 = w_lo; two MFMAs per t (B = x_hi plane, B = x_lo plane)
// accumulate all cross terms in fp32 -> error ~2^-15 rel, far below the
// existing h1->bf16 rounding (2^-9). conv2/pool2/conv3/logits bit-identical
// to R0/R6. Wave-private LDS arenas (hi/lo planes + tiny per-q h1 tile),
// ZERO barriers in the main loop; sh2 overlays the dead planes afterwards.
//   k0    : w2 -> w2b bf16 [64][96]; w3 -> w3b; w1 -> w1b [2][16][32] hi/lo
//   k_fused: per q: stage 16x128 floats -> hi/lo bf16 planes -> conv1 =
//     60 MFMA (15 t x 2 chhalf x hi/lo) + pool1 -> h1t [16][3][32] ->
//     conv2 = 12 MFMA vs w2b -> bias+relu+pool2 -> pk regs -> (after loop)
//     sh2 tile -> conv3 GEMM (K=256) vs w3b -> relu -> logits partials
//     -> wave butterfly -> per-block partial[512][3]
//   k_soft: 1 block: logits = partials[2b]+partials[2b+1]+bl, softmax.

typedef __attribute__((ext_vector_type(8))) short bf16x8;
typedef __attribute__((ext_vector_type(4))) float f32x4;

__device__ __forceinline__ ushort f2bf(float f) {
    union { float f; uint u; } c; c.f = f;
    return (ushort)((c.u + 0x7FFFu + ((c.u >> 16) & 1u)) >> 16);   // RNE
}

#define S2  264   // sh2 row stride (ushorts): 528B rows, 16B-aligned
#define XPS 136   // x hi/lo plane row stride (ushorts): 272B, 16B-aligned
#define H1S 104   // h1t row stride (ushorts): 208B; 52 dw -> 2-way-free banks

__global__ void k0_prep(const float* __restrict__ w2, ushort* __restrict__ w2b,
                        const float* __restrict__ w3, ushort* __restrict__ w3b,
                        const float* __restrict__ w1, ushort* __restrict__ w1b) {
    int i = blockIdx.x * 256 + threadIdx.x;
    if (i < 6144) {                     // w2[c][ci][d] -> w2b[c][d*32+ci]
        int c = i / 96, r = i - c * 96;
        int ci = r / 3, d = r - ci * 3;
        w2b[c * 96 + d * 32 + ci] = f2bf(w2[i]);
    }
    int j = i - 6144;
    if (j >= 0 && j < 32768) w3b[j] = f2bf(w3[j]);
    int j3 = i - 38912;                 // w1b[H][16 ch][32 k]: hi@3..12, lo@19..28
    if (j3 >= 0 && j3 < 1024) {
        int H = j3 >> 9, r9 = j3 & 511, c = r9 >> 5, k = r9 & 31;
        int ch = H * 16 + c;
        ushort val = 0;
        if (k >= 3 && k <= 12) {
            val = (ushort)(__float_as_uint(w1[ch * 10 + k - 3]) >> 16);  // hi=trunc
        } else if (k >= 19 && k <= 28) {
            float w = w1[ch * 10 + k - 19];
            float hf = __uint_as_float(__float_as_uint(w) & 0xFFFF0000u);
            val = f2bf(w - hf);                                          // lo=RNE
        }
        w1b[j3] = val;
    }
}

__global__ __launch_bounds__(256) void k_fused(
    const float* __restrict__ x,     // [32768][1216]
    const float* __restrict__ b1,    // [32]
    const ushort* __restrict__ w2b,  // [64][96] ; w1b at w2b+6144
    const float* __restrict__ b2,    // [64]
    const ushort* __restrict__ w3b,  // [128][256]
    const float* __restrict__ b3,    // [128]
    const float* __restrict__ wl,    // [3][16384]
    float* __restrict__ partials)    // [512][3]
{
    // per-wave arena: hi plane [16][XPS] | lo plane [16][XPS] | h1t [16][H1S]
    // = 2176 + 2176 + 1664 = 6016 ushorts (12032 B). sh2 (4224) overlays
    // the planes after the q loop (they are dead by then).
    __shared__ __align__(16) ushort arena[4][6016];
    __shared__ float red[4][3];
    const int wave = threadIdx.x >> 6, lane = threadIdx.x & 63;
    const int lm   = lane & 15, quad = lane >> 4, qm = quad & 1;
    const int bn0  = blockIdx.x * 64 + wave * 16;
    const float* xw0 = x + (size_t)bn0 * 1216;     // wave's 16 series rows

    ushort* hp  = arena[wave];            // x_hi plane
    ushort* lp  = hp + 16 * XPS;          // x_lo plane
    ushort* h1t = lp + 16 * XPS;          // per-q pooled conv1 tile [16][3][32]

    // hoisted fragments / biases
    const ushort* w1b = w2b + 6144;
    const bf16x8 wA0 = *(const bf16x8*)(w1b + lm * 32 + quad * 8);        // ch 0-15
    const bf16x8 wA1 = *(const bf16x8*)(w1b + 512 + lm * 32 + quad * 8);  // ch 16-31
    const f32x4  b1i0 = *(const f32x4*)(b1 + quad * 4);       // rows quad*4+r
    const f32x4  b1i1 = *(const f32x4*)(b1 + 16 + quad * 4);
    float bias2[4];
    #pragma unroll
    for (int nt = 0; nt < 4; ++nt) bias2[nt] = b2[nt * 16 + lm];

    f32x4 cur[4];
    #pragma unroll
    for (int nt = 0; nt < 4; ++nt) cur[nt] = (f32x4){-3e38f,-3e38f,-3e38f,-3e38f};
    uint2 pk[4][4];                       // packed pooled conv2 bf16 [nt][r]

    for (int q = 0; q < 10; ++q) {
        // ---- stage x[16 rows][fq .. fq+123] -> hi/lo bf16 planes ----
        // (wave-private: no barriers; 32 consecutive lanes cover one row)
        const int fq = 120 * q - 4;
        #pragma unroll
        for (int j = 0; j < 8; ++j) {
            const int idx = lane + 64 * j;          // 0..511
            const int row = idx >> 5, c4 = idx & 31;
            const int off = fq + 4 * c4;
            const float* src = xw0 + (size_t)row * 1216 + (off < 0 ? 0 : off);
            float4 v = *(const float4*)src;
            if (off < 0) v.w = 0.f;                 // x[-1] pad (j=3 slot)
            const uint ux = __float_as_uint(v.x), uy = __float_as_uint(v.y);
            const uint uz = __float_as_uint(v.z), uw = __float_as_uint(v.w);
            ushort4 hs = make_ushort4((ushort)(ux >> 16), (ushort)(uy >> 16),
                                      (ushort)(uz >> 16), (ushort)(uw >> 16));
            const float lx = v.x - __uint_as_float(ux & 0xFFFF0000u);
            const float ly = v.y - __uint_as_float(uy & 0xFFFF0000u);
            const float lz = v.z - __uint_as_float(uz & 0xFFFF0000u);
            const float lw = v.w - __uint_as_float(uw & 0xFFFF0000u);
            ushort4 ls = make_ushort4((ushort)(__float_as_uint(lx) >> 16),
                                      (ushort)(__float_as_uint(ly) >> 16),
                                      (ushort)(__float_as_uint(lz) >> 16),
                                      (ushort)(__float_as_uint(lw) >> 16));
            *(ushort4*)&hp[row * XPS + 4 * c4] = hs;
            *(ushort4*)&lp[row * XPS + 4 * c4] = ls;
        }

        // ---- conv1 MFMA + relu+pool5 -> h1t[series][tw][ch] ----
        // B-frag: lane(lm,quad) reads plane[lm][8*tl + 8*(quad&1)] (16B read)
        // giving B[k][s] = plane[s][8tl + (k mod 16)]; A slots 3..12 = w_hi,
        // 19..28 = w_lo -> D = sum_j w[j] * x[8t-4+3+j] = conv1(t).
        #pragma unroll
        for (int tw = 0; tw < 3; ++tw) {
            f32x4 mx0 = (f32x4){0.f,0.f,0.f,0.f};   // relu folded into pool
            f32x4 mx1 = (f32x4){0.f,0.f,0.f,0.f};
            #pragma unroll
            for (int ts = 0; ts < 5; ++ts) {
                const int tl = 5 * tw + ts;         // 0..14
                const int jb = 8 * tl + 8 * qm;
                bf16x8 bh = *(const bf16x8*)(hp + lm * XPS + jb);
                bf16x8 bl = *(const bf16x8*)(lp + lm * XPS + jb);
                f32x4 a0 = __builtin_amdgcn_mfma_f32_16x16x32_bf16(wA0, bh, b1i0, 0, 0, 0);
                a0 = __builtin_amdgcn_mfma_f32_16x16x32_bf16(wA0, bl, a0, 0, 0, 0);
                f32x4 a1 = __builtin_amdgcn_mfma_f32_16x16x32_bf16(wA1, bh, b1i1, 0, 0, 0);
                a1 = __builtin_amdgcn_mfma_f32_16x16x32_bf16(wA1, bl, a1, 0, 0, 0);
                #pragma unroll
                for (int r = 0; r < 4; ++r) {
                    mx0[r] = fmaxf(mx0[r], a0[r]);
                    mx1[r] = fmaxf(mx1[r], a1[r]);
                }
            }
            // D: col=lm (series), row=quad*4+r (ch) -> h1t[lm][tw][ch]
            ushort4 p0, p1;
            p0.x = f2bf(mx0[0]); p0.y = f2bf(mx0[1]);
            p0.z = f2bf(mx0[2]); p0.w = f2bf(mx0[3]);
            p1.x = f2bf(mx1[0]); p1.y = f2bf(mx1[1]);
            p1.z = f2bf(mx1[2]); p1.w = f2bf(mx1[3]);
            *(ushort4*)&h1t[lm * H1S + 32 * tw + quad * 4]      = p0;  // ch 0-15
            *(ushort4*)&h1t[lm * H1S + 32 * tw + 16 + quad * 4] = p1;  // ch 16-31
        }

        // ---- conv2: 12 MFMA vs w2b (A-frag from h1t, exact R0 layout) ----
        f32x4 acc[4];
        #pragma unroll
        for (int nt = 0; nt < 4; ++nt) acc[nt] = (f32x4){0.f,0.f,0.f,0.f};
        #pragma unroll
        for (int kc = 0; kc < 3; ++kc) {
            bf16x8 afv = *(const bf16x8*)&h1t[lm * H1S + 32 * kc + quad * 8];
            #pragma unroll
            for (int nt = 0; nt < 4; ++nt) {
                bf16x8 bfr = *(const bf16x8*)(w2b + (nt*16 + lm)*96 + kc*32 + quad*8);
                acc[nt] = __builtin_amdgcn_mfma_f32_16x16x32_bf16(afv, bfr, acc[nt], 0, 0, 0);
            }
        }

        // pool2 windows over q: {0,1},{2,3,4},{5,6,7},{8,9}  (wave-uniform)
        const bool fresh = (q == 0 || q == 2 || q == 5 || q == 8);
        #pragma unroll
        for (int nt = 0; nt < 4; ++nt)
            #pragma unroll
            for (int r = 0; r < 4; ++r)
                cur[nt][r] = fresh ? acc[nt][r] : fmaxf(cur[nt][r], acc[nt][r]);

        if (q == 1 || q == 4 || q == 7 || q == 9) {     // window close
            const int w = (q == 1) ? 0 : (q == 4) ? 1 : (q == 7) ? 2 : 3;
            #pragma unroll
            for (int nt = 0; nt < 4; ++nt)
                #pragma unroll
                for (int r = 0; r < 4; ++r) {
                    float f = fmaxf(cur[nt][r] + bias2[nt], 0.f);
                    uint hb = (uint)f2bf(f);
                    if (w == 0)      pk[nt][r].x  = hb;
                    else if (w == 1) pk[nt][r].x |= hb << 16;
                    else if (w == 2) pk[nt][r].y  = hb;
                    else             pk[nt][r].y |= hb << 16;
                }
        }
    }

    // ---- sh2 tile (overlays dead planes): rows = series, k = c2*4 + w ----
    ushort* shw = arena[wave];
    #pragma unroll
    for (int nt = 0; nt < 4; ++nt)
        #pragma unroll
        for (int r = 0; r < 4; ++r)
            *(uint2*)(shw + (quad*4 + r) * S2 + (nt*16 + lm) * 4) = pk[nt][r];

    // ---- conv3 GEMM (16 series x 128 cols, K=256) + logits partials ----
    bf16x8 afr[8];
    #pragma unroll
    for (int kc = 0; kc < 8; ++kc)          // A-frag: row lm, 16B contiguous
        afr[kc] = *(const bf16x8*)(shw + lm * S2 + kc * 32 + quad * 8);

    const int node0 = bn0 & 127;
    const float* wlr = wl + (node0 + quad * 4) * 128 + lm;
    float a0 = 0.f, a1 = 0.f, a2 = 0.f;
    for (int nt3 = 0; nt3 < 8; ++nt3) {     // dynamic: small icache
        f32x4 acc3 = (f32x4){0.f, 0.f, 0.f, 0.f};
        const ushort* bb = w3b + (size_t)(nt3 * 16 + lm) * 256 + quad * 8;
        #pragma unroll
        for (int kc = 0; kc < 8; ++kc) {
            bf16x8 bf3 = *(const bf16x8*)(bb + kc * 32);
            acc3 = __builtin_amdgcn_mfma_f32_16x16x32_bf16(afr[kc], bf3, acc3, 0, 0, 0);
        }
        const float b3v = b3[nt3 * 16 + lm];
        #pragma unroll
        for (int r = 0; r < 4; ++r) {       // feat value, never materialized
            float f = fmaxf(acc3[r] + b3v, 0.f);
            const float* wp = wlr + r * 128 + nt3 * 16;
            a0 = fmaf(f, wp[0],     a0);
            a1 = fmaf(f, wp[16384], a1);
            a2 = fmaf(f, wp[32768], a2);
        }
    }

    #pragma unroll
    for (int off = 32; off > 0; off >>= 1) {
        a0 += __shfl_xor(a0, off);
        a1 += __shfl_xor(a1, off);
        a2 += __shfl_xor(a2, off);
    }
    if (lane == 0) { red[wave][0] = a0; red[wave][1] = a1; red[wave][2] = a2; }
    __syncthreads();
    if (threadIdx.x < 3) {
        float s = red[0][threadIdx.x] + red[1][threadIdx.x]
                + red[2][threadIdx.x] + red[3][threadIdx.x];
        partials[blockIdx.x * 3 + threadIdx.x] = s;
    }
}

// logits = partials[2b] + partials[2b+1] + bl -> softmax
__global__ void k_soft(const float* __restrict__ partials,
                       const float* __restrict__ bl,
                       float* __restrict__ out) {
    const int b = threadIdx.x;      // 256 batches, 1 block
    float l0 = partials[(2*b)*3+0] + partials[(2*b+1)*3+0] + bl[0];
    float l1 = partials[(2*b)*3+1] + partials[(2*b+1)*3+1] + bl[1];
    float l2 = partials[(2*b)*3+2] + partials[(2*b+1)*3+2] + bl[2];
    float m  = fmaxf(l0, fmaxf(l1, l2));
    float e0 = expf(l0 - m), e1 = expf(l1 - m), e2 = expf(l2 - m);
    float s  = e0 + e1 + e2;
    out[b*3+0] = e0 / s; out[b*3+1] = e1 / s; out[b*3+2] = e2 / s;
}

extern "C" void kernel_launch(void* const* d_in, const int* in_sizes, int n_in,
                              void* d_out, int out_size, void* d_ws, size_t ws_size,
                              hipStream_t stream) {
    const float* x  = (const float*)d_in[0];
    const float* w1 = (const float*)d_in[1];
    const float* b1 = (const float*)d_in[2];
    const float* w2 = (const float*)d_in[3];
    const float* b2 = (const float*)d_in[4];
    const float* w3 = (const float*)d_in[5];
    const float* b3 = (const float*)d_in[6];
    const float* wl = (const float*)d_in[7];
    const float* bl = (const float*)d_in[8];
    float* out = (float*)d_out;

    // ws: [w2b 12KB | w1b 2KB (inside first 16KB slot)] | w3b 64KB | partials
    ushort* w2b      = (ushort*)d_ws;
    ushort* w1b      = w2b + 6144;
    ushort* w3b      = (ushort*)((char*)d_ws + 16384);
    float*  partials = (float*)((char*)d_ws + 16384 + 65536);

    k0_prep<<<156, 256, 0, stream>>>(w2, w2b, w3, w3b, w1, w1b);
    k_fused<<<512, 256, 0, stream>>>(x, b1, w2b, b2, w3b, b3, wl, partials);
    k_soft<<<1, 256, 0, stream>>>(partials, bl, out);
}